// Round 4
// baseline (340.349 us; speedup 1.0000x reference)
//
#include <hip/hip_runtime.h>

// Problem constants
#define CV   34          // C*V channels
#define TTOT 2048        // T
#define NB   512         // batches
#define XB   69632       // x per-batch stride (2*2048*17)
#define XC   34816       // x per-co stride (2048*17)

// Workspace layout (floats)
#define NSEG      16
#define P_STRIDE  1200                       // per-(batch,seg): G (1156) + s0 (34) + pad
#define RB_OFF    (NB * NSEG * P_STRIDE)     // region B offset (floats)
#define RB_STRIDE 1040                       // per-batch: Wy bf16 hi/lo planes (1024 f) + cy (16 f)

typedef __attribute__((ext_vector_type(8))) short v8s;   // 8 x bf16 (MFMA A/B frag)
typedef __attribute__((ext_vector_type(4))) float v4f;   // 4 x f32 (MFMA C/D frag)

__device__ __forceinline__ unsigned short f2bf(float f) {
    unsigned int u = __float_as_uint(f);
    u = u + 0x7FFFu + ((u >> 16) & 1u);   // round-to-nearest-even
    return (unsigned short)(u >> 16);
}
__device__ __forceinline__ float bf2f(unsigned short s) {
    return __uint_as_float(((unsigned int)s) << 16);
}

// ---------------------------------------------------------------------------
// K1: per-(batch, 128-t segment) partial Gram + row sums, ONE barrier.
// Waves own disjoint output tiles over full k=128: wave r in {0,1,2} computes
// G row-tiles (r, 0..2); wave 3 computes the 3 row-sum tiles. Wave-private
// stores to ws[b][seg] (no atomics, no cross-wave reduce). Rows 34..47 of the
// LDS tiles are uninitialized but only feed discarded m>=34 / n>=34 outputs.
// ---------------------------------------------------------------------------
__global__ __launch_bounds__(256) void k_gram(const float* __restrict__ x,
                                              float* __restrict__ ws) {
    __shared__ unsigned short Hh[48][152];   // row stride 304 B (16B-aligned)
    __shared__ unsigned short Hl[48][152];

    const int b    = blockIdx.x >> 4;
    const int sg   = blockIdx.x & 15;
    const int t0   = sg * 128;
    const int tid  = threadIdx.x;
    const int l    = tid & 63;
    const int w    = tid >> 6;
    const int row16 = l & 15;
    const int quad  = l >> 4;
    const float* xb = x + (size_t)b * XB;

    // stage: x[b,co,t0+t,v] -> H[co*17+v][t], bf16 hi/lo, float4 loads
    for (int i = tid; i < 1088; i += 256) {
        int co = (i >= 544);
        int j4 = i - co * 544;
        const float4 f4 = *(const float4*)(xb + co * XC + t0 * 17 + j4 * 4);
        const float fv[4] = {f4.x, f4.y, f4.z, f4.w};
#pragma unroll
        for (int e = 0; e < 4; ++e) {
            int j = j4 * 4 + e;
            int t = j / 17;
            int v = j - t * 17;
            float f = fv[e];
            unsigned short hb = f2bf(f);
            Hh[co * 17 + v][t] = hb;
            Hl[co * 17 + v][t] = f2bf(f - bf2f(hb));
        }
    }
    __syncthreads();

    float* pout = ws + ((size_t)b * NSEG + sg) * P_STRIDE;
    v4f vz = {0.f, 0.f, 0.f, 0.f};

    if (w < 3) {
        const int r = w;
        v4f accG[3] = {vz, vz, vz};
        for (int ks = 0; ks < 4; ++ks) {
            const int koff = ks * 32 + quad * 8;
            v8s fhr = *(const v8s*)&Hh[r * 16 + row16][koff];
            v8s flr = *(const v8s*)&Hl[r * 16 + row16][koff];
#pragma unroll
            for (int c = 0; c < 3; ++c) {
                v8s fhc = *(const v8s*)&Hh[c * 16 + row16][koff];
                v8s flc = *(const v8s*)&Hl[c * 16 + row16][koff];
                accG[c] = __builtin_amdgcn_mfma_f32_16x16x32_bf16(fhr, fhc, accG[c], 0, 0, 0);
                accG[c] = __builtin_amdgcn_mfma_f32_16x16x32_bf16(fhr, flc, accG[c], 0, 0, 0);
                accG[c] = __builtin_amdgcn_mfma_f32_16x16x32_bf16(flr, fhc, accG[c], 0, 0, 0);
            }
        }
        // D layout: row = quad*4+i, col = row16
#pragma unroll
        for (int c = 0; c < 3; ++c) {
#pragma unroll
            for (int i = 0; i < 4; ++i) {
                int m = r * 16 + quad * 4 + i;
                int n = c * 16 + row16;
                if (m < 34 && n < 34) pout[m * 34 + n] = accG[c][i];
            }
        }
    } else {
        v8s ones;
#pragma unroll
        for (int i = 0; i < 8; ++i) ones[i] = (short)0x3F80;   // bf16 1.0
        v4f accS[3] = {vz, vz, vz};
        for (int ks = 0; ks < 4; ++ks) {
            const int koff = ks * 32 + quad * 8;
#pragma unroll
            for (int r = 0; r < 3; ++r) {
                v8s fh = *(const v8s*)&Hh[r * 16 + row16][koff];
                v8s fl = *(const v8s*)&Hl[r * 16 + row16][koff];
                accS[r] = __builtin_amdgcn_mfma_f32_16x16x32_bf16(fh, ones, accS[r], 0, 0, 0);
                accS[r] = __builtin_amdgcn_mfma_f32_16x16x32_bf16(fl, ones, accS[r], 0, 0, 0);
            }
        }
        if (row16 == 0) {
#pragma unroll
            for (int r = 0; r < 3; ++r)
#pragma unroll
                for (int i = 0; i < 4; ++i) {
                    int m = r * 16 + quad * 4 + i;
                    if (m < 34) pout[1156 + m] = accS[r][i];
                }
        }
    }
}

// ---------------------------------------------------------------------------
// K2: per-batch affine chain (as round 3) + 16-partial G reduction on load.
// ---------------------------------------------------------------------------
__device__ __forceinline__ void mm24(const float L[][36], const float R[][36],
                                     float D[][36], int u) {
    int ti = u / 9, tj = u - ti * 9;      // u < 153
    int i0 = ti * 2, j0 = tj * 4;
    float acc[2][4] = {};
    for (int e0 = 0; e0 < 36; e0 += 4) {
        float4 lv[2], rv[4];
        lv[0] = *(const float4*)&L[i0][e0];
        lv[1] = *(const float4*)&L[i0 + 1][e0];
#pragma unroll
        for (int c = 0; c < 4; ++c) rv[c] = *(const float4*)&R[j0 + c][e0];
#pragma unroll
        for (int a = 0; a < 2; ++a)
#pragma unroll
            for (int c = 0; c < 4; ++c)
                acc[a][c] += lv[a].x * rv[c].x + lv[a].y * rv[c].y +
                             lv[a].z * rv[c].z + lv[a].w * rv[c].w;
    }
#pragma unroll
    for (int a = 0; a < 2; ++a)
#pragma unroll
        for (int c = 0; c < 4; ++c) D[i0 + a][j0 + c] = acc[a][c];
}

__device__ __forceinline__ void mmG4(const float* __restrict__ Lg,
                                     const float R[][36], float D[][36],
                                     int transpose, int u) {
    int ti = u / 9, tj = u - ti * 9;      // u < 81
    int i0 = ti * 4, j0 = tj * 4;
    float acc[4][4] = {};
    for (int e0 = 0; e0 < 32; e0 += 4) {
        float2 la[4], lb[4];
        float4 rv[4];
#pragma unroll
        for (int a = 0; a < 4; ++a) {
            int ri = i0 + a; ri = ri < 34 ? ri : 33;
            la[a] = *(const float2*)(Lg + ri * 34 + e0);
            lb[a] = *(const float2*)(Lg + ri * 34 + e0 + 2);
        }
#pragma unroll
        for (int c = 0; c < 4; ++c) rv[c] = *(const float4*)&R[j0 + c][e0];
#pragma unroll
        for (int a = 0; a < 4; ++a)
#pragma unroll
            for (int c = 0; c < 4; ++c)
                acc[a][c] += la[a].x * rv[c].x + la[a].y * rv[c].y +
                             lb[a].x * rv[c].z + lb[a].y * rv[c].w;
    }
    {   // tail e = 32,33
        float2 la[4];
#pragma unroll
        for (int a = 0; a < 4; ++a) {
            int ri = i0 + a; ri = ri < 34 ? ri : 33;
            la[a] = *(const float2*)(Lg + ri * 34 + 32);
        }
#pragma unroll
        for (int c = 0; c < 4; ++c) {
            float r0 = R[j0 + c][32], r1 = R[j0 + c][33];
#pragma unroll
            for (int a = 0; a < 4; ++a) acc[a][c] += la[a].x * r0 + la[a].y * r1;
        }
    }
#pragma unroll
    for (int a = 0; a < 4; ++a) {
        if (i0 + a < 34) {
#pragma unroll
            for (int c = 0; c < 4; ++c) {
                if (transpose) D[j0 + c][i0 + a] = acc[a][c];
                else           D[i0 + a][j0 + c] = acc[a][c];
            }
        }
    }
}

__global__ __launch_bounds__(256) void k_chain(
    const float* __restrict__ wq, const float* __restrict__ bq,
    const float* __restrict__ wk, const float* __restrict__ bk,
    const float* __restrict__ wv, const float* __restrict__ bv,
    const float* __restrict__ w1, const float* __restrict__ b1,
    const float* __restrict__ gamma, const float* __restrict__ beta,
    const float* __restrict__ mean, const float* __restrict__ var,
    float* __restrict__ ws) {
    __shared__ float G0b[36][36], At[36][36], Aq[36][36], Ak[36][36],
        AvT[36][36], S1[36][36], Sc[36][36];
    __shared__ float s0v[36], a_[36], aq_[36], ak_[36], avv_[36],
        qs_[36], ks_[36], invv[16];

    const int tid = threadIdx.x;
    const int b   = blockIdx.x;

    for (int i = tid; i < 1296; i += 256) {
        int m = i / 36, n = i - m * 36;
        G0b[m][n] = 0; At[m][n] = 0; Aq[m][n] = 0; Ak[m][n] = 0;
        AvT[m][n] = 0; S1[m][n] = 0; Sc[m][n] = 0;
    }
    if (tid < 36) {
        s0v[tid] = 0; a_[tid] = 0; aq_[tid] = 0; ak_[tid] = 0; avv_[tid] = 0;
        qs_[tid] = 0; ks_[tid] = 0;
    }
    __syncthreads();
    // load G0 (sum of 16 segment partials), s0; layer-0 shortcut: A = I
    const float* pb = ws + (size_t)b * NSEG * P_STRIDE;
    for (int i = tid; i < 1190; i += 256) {
        float s = 0;
#pragma unroll
        for (int sgi = 0; sgi < NSEG; ++sgi) s += pb[sgi * P_STRIDE + i];
        if (i < 1156) {
            int m = i / 34;
            G0b[m][i - m * 34] = s;
        } else {
            s0v[i - 1156] = s;
        }
    }
    for (int i = tid; i < 1156; i += 256) {
        int m = i / 34, n = i - m * 34;
        Aq[m][n] = wq[i]; Ak[m][n] = wk[i]; AvT[n][m] = wv[i];
    }
    if (tid < 34) {
        aq_[tid] = bq[tid]; ak_[tid] = bk[tid]; avv_[tid] = bv[tid];
    }
    __syncthreads();

    for (int lyr = 0; lyr < 3; ++lyr) {
        const float* wql = wq + lyr * 1156;
        const float* wkl = wk + lyr * 1156;
        const float* wvl = wv + lyr * 1156;
        if (lyr > 0) {
            if (tid < 243) {
                int g = tid / 81, u = tid - g * 81;
                const float* Lg = (g == 0) ? wql : (g == 1) ? wkl : wvl;
                float (*D)[36] = (g == 0) ? Aq : (g == 1) ? Ak : AvT;
                mmG4(Lg, At, D, g == 2, u);
            }
            __syncthreads();
        }
        if (tid < 153) {
            mm24(Aq, G0b, S1, tid);
        } else if (lyr > 0 && tid < 255) {
            int u = tid - 153, r = u / 34, c = u - r * 34;
            const float* wrow = ((r == 0) ? wql : (r == 1) ? wkl : wvl) + c * 34;
            float s = 0;
            for (int e = 0; e < 34; ++e) s += wrow[e] * a_[e];
            float bb = (r == 0) ? bq[lyr * 34 + c]
                     : (r == 1) ? bk[lyr * 34 + c] : bv[lyr * 34 + c];
            if (r == 0) aq_[c] = s + bb;
            else if (r == 1) ak_[c] = s + bb;
            else avv_[c] = s + bb;
        }
        __syncthreads();
        if (tid < 153) {
            mm24(S1, Ak, Sc, tid);
        } else if (tid >= 160 && tid < 228) {
            int u = tid - 160, r = u / 34, c = u - r * 34;
            const float (*M)[36] = r ? Ak : Aq;
            float s = 0;
            for (int e = 0; e < 34; ++e) s += M[c][e] * s0v[e];
            if (r == 0) qs_[c] = s; else ks_[c] = s;
        }
        __syncthreads();
        if (tid < 34) {
            const int c = tid;
            const float scale = 0.022097086912079608f;   // 1/sqrt(2048)
            float mx = -1e30f;
            for (int d = 0; d < 34; ++d) {
                float v = (Sc[c][d] + qs_[c] * ak_[d] + aq_[c] * ks_[d] +
                           2048.0f * aq_[c] * ak_[d]) * scale;
                Sc[c][d] = v;
                mx = fmaxf(mx, v);
            }
            float sum = 0;
            for (int d = 0; d < 34; ++d) {
                float e = __expf(Sc[c][d] - mx);
                Sc[c][d] = e;
                sum += e;
            }
            float rs = 1.0f / sum;
            for (int d = 0; d < 34; ++d) Sc[c][d] *= rs;
        }
        __syncthreads();
        if (tid < 153) {
            mm24(AvT, Sc, At, tid);
        } else if (tid >= 160 && tid < 194) {
            int c = tid - 160;
            float s = 0;
            for (int d = 0; d < 34; ++d) s += Sc[c][d] * avv_[d];
            a_[c] = s;
        }
        __syncthreads();
    }

    if (tid < 72) {
        int ti = tid / 9, tj = tid - ti * 9;
        int i0 = ti * 2, j0 = tj * 4;
        float acc[2][4] = {};
        for (int e0 = 0; e0 < 32; e0 += 4) {
            float2 la[2], lb[2];
            float4 rv[4];
#pragma unroll
            for (int a = 0; a < 2; ++a) {
                la[a] = *(const float2*)(w1 + (i0 + a) * 34 + e0);
                lb[a] = *(const float2*)(w1 + (i0 + a) * 34 + e0 + 2);
            }
#pragma unroll
            for (int c = 0; c < 4; ++c) rv[c] = *(const float4*)&At[j0 + c][e0];
#pragma unroll
            for (int a = 0; a < 2; ++a)
#pragma unroll
                for (int c = 0; c < 4; ++c)
                    acc[a][c] += la[a].x * rv[c].x + la[a].y * rv[c].y +
                                 lb[a].x * rv[c].z + lb[a].y * rv[c].w;
        }
        {
            float2 la[2];
#pragma unroll
            for (int a = 0; a < 2; ++a)
                la[a] = *(const float2*)(w1 + (i0 + a) * 34 + 32);
#pragma unroll
            for (int c = 0; c < 4; ++c) {
                float r0 = At[j0 + c][32], r1 = At[j0 + c][33];
#pragma unroll
                for (int a = 0; a < 2; ++a) acc[a][c] += la[a].x * r0 + la[a].y * r1;
            }
        }
#pragma unroll
        for (int a = 0; a < 2; ++a)
#pragma unroll
            for (int c = 0; c < 4; ++c) S1[i0 + a][j0 + c] = acc[a][c];
    } else if (tid < 88) {
        int o = tid - 72;
        invv[o] = gamma[o] * rsqrtf(var[o] + 1e-5f);
    } else if (tid < 104) {
        int o = tid - 88;
        float s = 0;
        for (int e = 0; e < 34; ++e) s += w1[o * 34 + e] * a_[e];
        ks_[o] = s + b1[o];          // raw cy
    }
    __syncthreads();
    float* wb = ws + RB_OFF + (size_t)b * RB_STRIDE;
    if (tid < 16)
        wb[1024 + tid] = (ks_[tid] - mean[tid]) * invv[tid] + beta[tid];
    unsigned short* wp = (unsigned short*)wb;
    for (int i = tid; i < 1024; i += 256) {
        int o = i >> 6, c = i & 63;
        float vv = (c < 34) ? S1[o][c] * invv[o] : 0.0f;
        unsigned short hb = f2bf(vv);
        wp[i] = hb;
        wp[1024 + i] = f2bf(vv - bf2f(hb));
    }
}

// ---------------------------------------------------------------------------
// K3: out = w2 * leaky(Wy' h0 + cy') + b2. One 128-t chunk per block,
// single barrier. grid = 512 b x 16 segments.
// ---------------------------------------------------------------------------
__global__ __launch_bounds__(256) void k_out(const float* __restrict__ x,
                                             const float* __restrict__ w2,
                                             const float* __restrict__ b2,
                                             const float* __restrict__ ws,
                                             float* __restrict__ out) {
    __shared__ unsigned short HtH[128][72];
    __shared__ unsigned short HtL[128][72];

    const int tid  = threadIdx.x;
    const int b    = blockIdx.x >> 4;
    const int t0   = (blockIdx.x & 15) * 128;
    const int l    = tid & 63;
    const int w    = tid >> 6;
    const int quad = l >> 4;
    const int col  = l & 15;

    const float* wb = ws + RB_OFF + (size_t)b * RB_STRIDE;
    const unsigned short* wp = (const unsigned short*)wb;
    v8s aH[2], aL[2];
#pragma unroll
    for (int ks = 0; ks < 2; ++ks) {
        aH[ks] = *(const v8s*)&wp[col * 64 + ks * 32 + quad * 8];
        aL[ks] = *(const v8s*)&wp[1024 + col * 64 + ks * 32 + quad * 8];
    }
    float cyr[4], w2r[3][4];
#pragma unroll
    for (int i = 0; i < 4; ++i) {
        int o = quad * 4 + i;
        cyr[i] = wb[1024 + o];
#pragma unroll
        for (int p = 0; p < 3; ++p) w2r[p][i] = w2[p * 16 + o];
    }
    float b2r[3] = {b2[0], b2[1], b2[2]};
    const float* xb = x + (size_t)b * XB;

    // zero channel pad cols 34..63
    for (int idx = tid; idx < 128 * 30; idx += 256) {
        int t = idx / 30;
        int c = 34 + (idx - t * 30);
        HtH[t][c] = 0;
        HtL[t][c] = 0;
    }
    // stage chunk
    for (int i = tid; i < 1088; i += 256) {
        int co = (i >= 544);
        int j4 = i - co * 544;
        const float4 f4 = *(const float4*)(xb + co * XC + t0 * 17 + j4 * 4);
        const float fv[4] = {f4.x, f4.y, f4.z, f4.w};
#pragma unroll
        for (int e = 0; e < 4; ++e) {
            int j = j4 * 4 + e;
            int t = j / 17;
            int v = j - t * 17;
            float f = fv[e];
            unsigned short hb = f2bf(f);
            HtH[t][co * 17 + v] = hb;
            HtL[t][co * 17 + v] = f2bf(f - bf2f(hb));
        }
    }
    __syncthreads();

    for (int tt = w; tt < 8; tt += 4) {
        const int tBase = tt * 16;
        v4f acc = {0.f, 0.f, 0.f, 0.f};
#pragma unroll
        for (int ks = 0; ks < 2; ++ks) {
            v8s bH = *(const v8s*)&HtH[tBase + col][ks * 32 + quad * 8];
            v8s bL = *(const v8s*)&HtL[tBase + col][ks * 32 + quad * 8];
            acc = __builtin_amdgcn_mfma_f32_16x16x32_bf16(aH[ks], bH, acc, 0, 0, 0);
            acc = __builtin_amdgcn_mfma_f32_16x16x32_bf16(aH[ks], bL, acc, 0, 0, 0);
            acc = __builtin_amdgcn_mfma_f32_16x16x32_bf16(aL[ks], bH, acc, 0, 0, 0);
        }
        float op[3] = {0, 0, 0};
#pragma unroll
        for (int i = 0; i < 4; ++i) {
            float y = acc[i] + cyr[i];
            float z = (y > 0.f) ? y : 0.01f * y;
#pragma unroll
            for (int p = 0; p < 3; ++p) op[p] += w2r[p][i] * z;
        }
#pragma unroll
        for (int p = 0; p < 3; ++p) {
            op[p] += __shfl_xor(op[p], 16);
            op[p] += __shfl_xor(op[p], 32);
        }
        if (l < 16) {
            int tg = t0 + tBase + l;
#pragma unroll
            for (int p = 0; p < 3; ++p)
                out[((size_t)b * 3 + p) * 2048 + tg] = op[p] + b2r[p];
        }
    }
}

extern "C" void kernel_launch(void* const* d_in, const int* in_sizes, int n_in,
                              void* d_out, int out_size, void* d_ws, size_t ws_size,
                              hipStream_t stream) {
    const float* x     = (const float*)d_in[0];
    const float* wq    = (const float*)d_in[1];
    const float* bq    = (const float*)d_in[2];
    const float* wk    = (const float*)d_in[3];
    const float* bk    = (const float*)d_in[4];
    const float* wv    = (const float*)d_in[5];
    const float* bv    = (const float*)d_in[6];
    const float* w1    = (const float*)d_in[7];
    const float* b1    = (const float*)d_in[8];
    const float* gamma = (const float*)d_in[9];
    const float* beta  = (const float*)d_in[10];
    const float* mean  = (const float*)d_in[11];
    const float* var   = (const float*)d_in[12];
    const float* w2    = (const float*)d_in[13];
    const float* b2    = (const float*)d_in[14];
    float* ws  = (float*)d_ws;
    float* out = (float*)d_out;

    k_gram<<<dim3(NB * NSEG), dim3(256), 0, stream>>>(x, ws);
    k_chain<<<dim3(NB), dim3(256), 0, stream>>>(wq, bq, wk, bk, wv, bv,
                                                w1, b1, gamma, beta, mean, var, ws);
    k_out<<<dim3(NB * NSEG), dim3(256), 0, stream>>>(x, w2, b2, ws, out);
}